// Round 9
// baseline (1844.978 us; speedup 1.0000x reference)
//
#include <hip/hip_runtime.h>

#define V 512
#define L 168
#define PLANE 86016          // V*L
#define CHSTRIDE 2752512     // 32*512*168 elements per batch
#define NFLAT 5376           // 32*168
#define B_ 16
#define HDRB (1u << 20)      // ATb (512 KB) + Wb (8 KB), padded to 1 MiB

typedef __attribute__((ext_vector_type(8))) short s16x8;
typedef __attribute__((ext_vector_type(4))) float f32x4;
typedef unsigned short u16;

__device__ inline short f2bf(float f) {
    unsigned u = __builtin_bit_cast(unsigned, f);
    u += 0x7FFF + ((u >> 16) & 1);
    return (short)(u >> 16);
}

__device__ inline void gll16(const u16* g, u16* lds) {
    __builtin_amdgcn_global_load_lds(
        (const __attribute__((address_space(1))) void*)g,
        (__attribute__((address_space(3))) void*)lds, 16, 0, 0);
}

// ---- prep: ATb[w][v] = bf16(rownorm adj^T); Wb = folded W' (mix absorbed) ----
__global__ __launch_bounds__(256) void prep_b(const float* __restrict__ adj,
                                              const float* __restrict__ W,
                                              u16* __restrict__ ATb,
                                              u16* __restrict__ Wb) {
    if (blockIdx.x == V) {
        const float al = 0.05f, be = 0.95f;
        for (int i = threadIdx.x; i < 1024; i += 256) {
            const int o = i >> 5, c = i & 31;
            const float w0 = W[o * 128 + c];
            const float w1 = W[o * 128 + 32 + c];
            const float w2 = W[o * 128 + 64 + c];
            const float w3 = W[o * 128 + 96 + c];
            Wb[o * 128 + c]      = f2bf(w0 + al * (w1 + w2 + w3));
            Wb[o * 128 + 32 + c] = f2bf(be * (w1 + al * (w2 + w3)));
            Wb[o * 128 + 64 + c] = f2bf(be * be * (w2 + al * w3));
            Wb[o * 128 + 96 + c] = f2bf(be * be * be * w3);
        }
        return;
    }
    const int v = blockIdx.x;
    float s = 0.f;
    for (int w = threadIdx.x; w < V; w += 256)
        s += adj[v * V + w] + (w == v ? 1.f : 0.f);
    __shared__ float red[256];
    red[threadIdx.x] = s;
    __syncthreads();
    for (int off = 128; off > 0; off >>= 1) {
        if ((int)threadIdx.x < off) red[threadIdx.x] += red[threadIdx.x + off];
        __syncthreads();
    }
    const float inv = 1.f / red[0];
    for (int w = threadIdx.x; w < V; w += 256)
        ATb[w * V + v] = f2bf((adj[v * V + w] + (w == v ? 1.f : 0.f)) * inv);
}

// ---- cvtT: xa[b][n=(c,l)][v] = bf16(x[b][c][v][l]) — LDS-tiled transpose -----
__global__ __launch_bounds__(256) void cvtT(const float* __restrict__ x,
                                            u16* __restrict__ xa) {
    const int b = blockIdx.z >> 5, c = blockIdx.z & 31;
    const int v0 = blockIdx.y * 64, l0 = blockIdx.x * 64;
    const int tid = threadIdx.x;
    __shared__ float T[64][65];
    const float* xp = x + (size_t)b * CHSTRIDE + (size_t)c * PLANE;
    u16* xo = xa + (size_t)b * CHSTRIDE + (size_t)c * L * 512;

#pragma unroll
    for (int rep = 0; rep < 16; rep++) {
        const int idx = rep * 256 + tid;
        const int vv = idx >> 6, ll = idx & 63;
        if (l0 + ll < L) T[vv][ll] = xp[(size_t)(v0 + vv) * L + l0 + ll];
    }
    __syncthreads();
#pragma unroll
    for (int rep = 0; rep < 16; rep++) {
        const int idx = rep * 256 + tid;
        const int ll = idx >> 6, vv = idx & 63;
        if (l0 + ll < L)
            xo[(size_t)(l0 + ll) * 512 + v0 + vv] = f2bf(T[vv][ll]);
    }
}

// ---- prop: dst[n][v] = bf16(AT @ src), src/dst [n][v] — m97-style -------------
// 128x128 tile, BK=64, global_load_lds staging for A and B, 2 barriers/step.
// Grid x: 4 w-tiles adjacent per n-tile (same src panel -> same XCD L2).
__global__ __launch_bounds__(256, 2) void prop_m(const u16* __restrict__ src,
                                                 const u16* __restrict__ ATb,
                                                 u16* __restrict__ dst) {
    const int b = blockIdx.z;
    const int n0 = (blockIdx.x >> 2) * 128, w0 = (blockIdx.x & 3) * 128;
    const int tid = threadIdx.x, lane = tid & 63, wave = tid >> 6;
    const int wm = wave >> 1, wn = wave & 1;
    const int colb = lane & 15, kg = lane >> 4;
    __shared__ __align__(16) u16 As[8 * 128 * 8];   // [oct][w][8], 16 KB
    __shared__ __align__(16) u16 Bs[8 * 128 * 8];   // [oct][n][8], 16 KB
    const size_t sB = (size_t)b * CHSTRIDE;
    const u16* srcb = src + sB;

    f32x4 acc[4][4];
#pragma unroll
    for (int i = 0; i < 4; i++)
#pragma unroll
        for (int j = 0; j < 4; j++) acc[i][j] = (f32x4){0.f, 0.f, 0.f, 0.f};

    for (int v0 = 0; v0 < V; v0 += 64) {
        __syncthreads();   // prev-iter LDS reads complete before overwrite
#pragma unroll
        for (int i = 0; i < 4; i++) {
            const int c = wave * 4 + i, oct = c >> 1, half = c & 1;
            const int row = half * 64 + lane;
            gll16(&ATb[(size_t)(w0 + row) * 512 + v0 + oct * 8],
                  &As[oct * 1024 + half * 512]);
            gll16(&srcb[(size_t)(n0 + row) * 512 + v0 + oct * 8],
                  &Bs[oct * 1024 + half * 512]);
        }
        __syncthreads();   // staging (vmcnt-drained by compiler) visible
#pragma unroll
        for (int kk = 0; kk < 2; kk++) {
            const int cq = kk * 4 + kg;
            s16x8 afr[4], bfr[4];
#pragma unroll
            for (int mt = 0; mt < 4; mt++)
                afr[mt] = *(const s16x8*)&As[cq * 1024 + (wm * 64 + mt * 16 + colb) * 8];
#pragma unroll
            for (int nt = 0; nt < 4; nt++)
                bfr[nt] = *(const s16x8*)&Bs[cq * 1024 + (wn * 64 + nt * 16 + colb) * 8];
#pragma unroll
            for (int mt = 0; mt < 4; mt++)
#pragma unroll
                for (int nt = 0; nt < 4; nt++)
                    acc[mt][nt] = __builtin_amdgcn_mfma_f32_16x16x32_bf16(afr[mt], bfr[nt],
                                                                          acc[mt][nt], 0, 0, 0);
        }
    }

    // store [n][v]: lane col n = .. + colb, rows w = wrow..+3 -> one 8B store
#pragma unroll
    for (int mt = 0; mt < 4; mt++) {
        const int wrow = w0 + wm * 64 + mt * 16 + kg * 4;
#pragma unroll
        for (int nt = 0; nt < 4; nt++) {
            const int n = n0 + wn * 64 + nt * 16 + colb;
            ushort4 pk;
            pk.x = (u16)f2bf(acc[mt][nt][0]);
            pk.y = (u16)f2bf(acc[mt][nt][1]);
            pk.z = (u16)f2bf(acc[mt][nt][2]);
            pk.w = (u16)f2bf(acc[mt][nt][3]);
            *(ushort4*)&dst[sB + (size_t)n * 512 + wrow] = pk;
        }
    }
}

// ---- outconv: out = bias + W' @ [x(f32 [c][v][l]), p1,p2,p3 ([n][v])] --------
__global__ __launch_bounds__(256) void outconv_b(const float* __restrict__ x,
                                                 const u16* __restrict__ p1,
                                                 const u16* __restrict__ p2,
                                                 const u16* __restrict__ p3,
                                                 const u16* __restrict__ Wb,
                                                 const float* __restrict__ bias,
                                                 float* __restrict__ out) {
    const int b = blockIdx.y, p0 = blockIdx.x * 64;
    const int tid = threadIdx.x, lane = tid & 63, wave = tid >> 6;
    const int colb = lane & 15, kg = lane >> 4;
    __shared__ __align__(16) u16 Hs[16 * 64 * 8];  // 16 KB
    const size_t bH = (size_t)b * CHSTRIDE;
    const u16* bufs[4] = {nullptr, p1, p2, p3};

    {
        const int pos = p0 + (tid & 63);
        const int v = pos / L, l = pos - v * L;
        const int cb = wave * 8;                 // channel octet within buffer
#pragma unroll
        for (int p = 0; p < 4; p++) {
            const int m = wave + p * 4;
            s16x8 t;
            if (p == 0) {
                const float* srcx = x + bH + (size_t)cb * PLANE + pos;
#pragma unroll
                for (int j = 0; j < 8; j++) t[j] = f2bf(srcx[(size_t)j * PLANE]);
            } else {
                const u16* srch = bufs[p] + bH;
#pragma unroll
                for (int j = 0; j < 8; j++)
                    t[j] = (short)srch[((size_t)(cb + j) * L + l) * 512 + v];
            }
            *(s16x8*)&Hs[m * 512 + (tid & 63) * 8] = t;
        }
    }
    __syncthreads();

    f32x4 acc[2];
    acc[0] = (f32x4){0.f, 0.f, 0.f, 0.f};
    acc[1] = acc[0];
#pragma unroll
    for (int kk = 0; kk < 4; kk++) {
        const s16x8 bfr = *(const s16x8*)&Hs[(kk * 4 + kg) * 512 + (wave * 16 + colb) * 8];
#pragma unroll
        for (int mt = 0; mt < 2; mt++) {
            const s16x8 afr = *(const s16x8*)&Wb[(mt * 16 + colb) * 128 + kk * 32 + kg * 8];
            acc[mt] = __builtin_amdgcn_mfma_f32_16x16x32_bf16(afr, bfr, acc[mt], 0, 0, 0);
        }
    }
#pragma unroll
    for (int mt = 0; mt < 2; mt++)
#pragma unroll
        for (int r = 0; r < 4; r++) {
            const int o = mt * 16 + kg * 4 + r;
            out[bH + (size_t)o * PLANE + p0 + wave * 16 + colb] = bias[o] + acc[mt][r];
        }
}

extern "C" void kernel_launch(void* const* d_in, const int* in_sizes, int n_in,
                              void* d_out, int out_size, void* d_ws, size_t ws_size,
                              hipStream_t stream) {
    const float* x = (const float*)d_in[0];
    const float* adj = (const float*)d_in[1];
    const float* W = (const float*)d_in[2];
    const float* bias = (const float*)d_in[3];
    float* out = (float*)d_out;

    char* ws = (char*)d_ws;
    u16* ATb = (u16*)ws;
    u16* Wb = (u16*)(ws + 524288);
    u16* hbuf = (u16*)(ws + HDRB);

    prep_b<<<V + 1, 256, 0, stream>>>(adj, W, ATb, Wb);

    const size_t perBuf = (size_t)CHSTRIDE * 2;      // bytes per batch per bf16 buffer
    const size_t avail = ws_size > HDRB ? ws_size - HDRB : 0;
    int nbc = (int)(avail / (4 * perBuf));           // xa + p1 + p2 + p3
    if (nbc < 1) nbc = 1;                            // requires ws >= ~23 MB
    if (nbc > B_) nbc = B_;

    for (int b0 = 0; b0 < B_; b0 += nbc) {
        const int nb = (B_ - b0 < nbc) ? (B_ - b0) : nbc;
        const float* xb = x + (size_t)b0 * CHSTRIDE;
        float* outb = out + (size_t)b0 * CHSTRIDE;
        u16* xa = hbuf;
        u16* p1 = hbuf + (size_t)nbc * CHSTRIDE;
        u16* p2 = hbuf + (size_t)2 * nbc * CHSTRIDE;
        u16* p3 = hbuf + (size_t)3 * nbc * CHSTRIDE;

        cvtT<<<dim3(3, 8, nb * 32), 256, 0, stream>>>(xb, xa);

        const dim3 pg(168, 1, nb);                   // 42 n-tiles x 4 w-tiles
        prop_m<<<pg, 256, 0, stream>>>(xa, ATb, p1);
        prop_m<<<pg, 256, 0, stream>>>(p1, ATb, p2);
        prop_m<<<pg, 256, 0, stream>>>(p2, ATb, p3);

        outconv_b<<<dim3(PLANE / 64, nb), 256, 0, stream>>>(xb, p1, p2, p3, Wb, bias, outb);
    }
}

// Round 10
// 645.658 us; speedup vs baseline: 2.8575x; 2.8575x over previous
//
#include <hip/hip_runtime.h>

#define V 512
#define L 168
#define PLANE 86016          // 512*168 (per-channel plane, both layouts)
#define CHSTRIDE 2752512     // 32*512*168 elements per batch
#define B_ 16
#define HDRB (1u << 20)      // ATb (512 KB) + Wb (8 KB), padded to 1 MiB

typedef __attribute__((ext_vector_type(8))) short s16x8;
typedef __attribute__((ext_vector_type(4))) float f32x4;
typedef unsigned short u16;

__device__ inline short f2bf(float f) {
    unsigned u = __builtin_bit_cast(unsigned, f);
    u += 0x7FFF + ((u >> 16) & 1);
    return (short)(u >> 16);
}

__device__ inline void gll16(const u16* g, u16* lds) {
    __builtin_amdgcn_global_load_lds(
        (const __attribute__((address_space(1))) void*)g,
        (__attribute__((address_space(3))) void*)lds, 16, 0, 0);
}

// ---- prep: ATb[w][v] = bf16(anorm[v][w]); Wb = folded W' (mix absorbed) ------
// out = b + W0'p0 + W1'p1 + W2'p2 + W3'p3,  p0=x, p_k = "A-prop" of p_{k-1}
__global__ __launch_bounds__(256) void prep_b(const float* __restrict__ adj,
                                              const float* __restrict__ W,
                                              u16* __restrict__ ATb,
                                              u16* __restrict__ Wb) {
    if (blockIdx.x == V) {
        const float al = 0.05f, be = 0.95f;
        for (int i = threadIdx.x; i < 1024; i += 256) {
            const int o = i >> 5, c = i & 31;
            const float w0 = W[o * 128 + c];
            const float w1 = W[o * 128 + 32 + c];
            const float w2 = W[o * 128 + 64 + c];
            const float w3 = W[o * 128 + 96 + c];
            Wb[o * 128 + c]      = f2bf(w0 + al * (w1 + w2 + w3));
            Wb[o * 128 + 32 + c] = f2bf(be * (w1 + al * (w2 + w3)));
            Wb[o * 128 + 64 + c] = f2bf(be * be * (w2 + al * w3));
            Wb[o * 128 + 96 + c] = f2bf(be * be * be * w3);
        }
        return;
    }
    const int v = blockIdx.x;
    float s = 0.f;
    for (int w = threadIdx.x; w < V; w += 256)
        s += adj[v * V + w] + (w == v ? 1.f : 0.f);
    __shared__ float red[256];
    red[threadIdx.x] = s;
    __syncthreads();
    for (int off = 128; off > 0; off >>= 1) {
        if ((int)threadIdx.x < off) red[threadIdx.x] += red[threadIdx.x + off];
        __syncthreads();
    }
    const float inv = 1.f / red[0];
    for (int w = threadIdx.x; w < V; w += 256)
        ATb[w * V + v] = f2bf((adj[v * V + w] + (w == v ? 1.f : 0.f)) * inv);
}

// ---- cvtT: xa[b][(c,l)][v] = bf16(x[b][c][v][l]) — LDS-tiled (r7-proven) -----
__global__ __launch_bounds__(256) void cvtT(const float* __restrict__ x,
                                            u16* __restrict__ xa) {
    const int b = blockIdx.z >> 5, c = blockIdx.z & 31;
    const int v0 = blockIdx.y * 64, l0 = blockIdx.x * 64;
    const int tid = threadIdx.x;
    __shared__ float T[64][65];
    const float* xp = x + (size_t)b * CHSTRIDE + (size_t)c * PLANE;
    u16* xo = xa + (size_t)b * CHSTRIDE + (size_t)c * L * 512;

#pragma unroll
    for (int rep = 0; rep < 16; rep++) {
        const int idx = rep * 256 + tid;
        const int vv = idx >> 6, ll = idx & 63;
        if (l0 + ll < L) T[vv][ll] = xp[(size_t)(v0 + vv) * L + l0 + ll];
    }
    __syncthreads();
#pragma unroll
    for (int rep = 0; rep < 16; rep++) {
        const int idx = rep * 256 + tid;
        const int ll = idx >> 6, vv = idx & 63;
        if (l0 + ll < L)
            xo[(size_t)(l0 + ll) * 512 + v0 + vv] = f2bf(T[vv][ll]);
    }
}

// ---- mega: per (b, l-pair): Y0=xa slab; Y_s chained in LDS; out-acc fused ----
// Rows: row=(c<<1)|lp2, 64 rows x 512 v per Y buffer (64 KB), ping-pong.
// Swizzle (all paths): element (row,e): addr = row*512 + ((e>>3)^(row&15))*8 + (e&7).
__global__ __launch_bounds__(512, 2) void mega(const u16* __restrict__ xa,
                                               const u16* __restrict__ ATb,
                                               const u16* __restrict__ Wb,
                                               const float* __restrict__ bias,
                                               float* __restrict__ tmp) {
    const int lp = blockIdx.x, b = blockIdx.y;
    const int tid = threadIdx.x, lane = tid & 63, wave = tid >> 6;
    const int colb = lane & 15, kg = lane >> 4;
    __shared__ __align__(16) u16 Y[2][64 * 512];   // 131072 B
    const size_t bH = (size_t)b * CHSTRIDE;

    // ---- stage Y0 <- xa slab: linear LDS dest, pre-swizzled global source ----
#pragma unroll
    for (int p = 0; p < 8; p++) {
        const int row = p * 8 + wave;              // wave-uniform
        const int c = row >> 1, l = lp * 2 + (row & 1);
        gll16(xa + bH + ((size_t)c * L + l) * 512 + ((lane ^ (row & 15)) << 3),
              &Y[0][row * 512 + lane * 8]);
    }
    __syncthreads();

    f32x4 aco[2][8];                               // out acc: 32 o x 128 pos per wave
#pragma unroll
    for (int i = 0; i < 2; i++)
#pragma unroll
        for (int j = 0; j < 8; j++) aco[i][j] = (f32x4){0.f, 0.f, 0.f, 0.f};

    // OUTACC stage S from buffer BUF: aco += W'_S (x) Y[BUF]  (k = c, one MFMA)
#define OUTACC(S, BUF)                                                             \
    {                                                                              \
        _Pragma("unroll") for (int nt = 0; nt < 8; nt++) {                         \
            const int lp2 = nt >> 2;                                               \
            const int w = wave * 64 + (nt & 3) * 16 + colb;                        \
            s16x8 bfr;                                                             \
            _Pragma("unroll") for (int j = 0; j < 8; j++) {                        \
                const int row = ((kg * 8 + j) << 1) | lp2;                         \
                bfr[j] = (short)Y[BUF][row * 512 +                                 \
                                       (((w >> 3) ^ (row & 15)) << 3) + (w & 7)];  \
            }                                                                      \
            _Pragma("unroll") for (int mt = 0; mt < 2; mt++) {                     \
                const s16x8 afr = *(const s16x8*)&Wb[(mt * 16 + colb) * 128 +      \
                                                     (S) * 32 + kg * 8];           \
                aco[mt][nt] = __builtin_amdgcn_mfma_f32_16x16x32_bf16(             \
                    afr, bfr, aco[mt][nt], 0, 0, 0);                               \
            }                                                                      \
        }                                                                          \
    }

    // GEMM: Y[WR] = bf16( Y[RD] x ATb^T )  (contraction over v; wave owns 64 w)
#define GEMM(RD, WR)                                                               \
    {                                                                              \
        f32x4 acc[4][4];                                                           \
        _Pragma("unroll") for (int i = 0; i < 4; i++)                              \
            _Pragma("unroll") for (int j = 0; j < 4; j++)                          \
                acc[i][j] = (f32x4){0.f, 0.f, 0.f, 0.f};                           \
        _Pragma("unroll 4") for (int kk = 0; kk < 16; kk++) {                      \
            s16x8 afr[4], bfr[4];                                                  \
            _Pragma("unroll") for (int mt = 0; mt < 4; mt++) {                     \
                const int row = mt * 16 + colb;                                    \
                afr[mt] = *(const s16x8*)&Y[RD][row * 512 +                        \
                                                (((kk * 4 + kg) ^ (row & 15)) << 3)]; \
            }                                                                      \
            _Pragma("unroll") for (int nt = 0; nt < 4; nt++) {                     \
                const int w = wave * 64 + nt * 16 + colb;                          \
                bfr[nt] = *(const s16x8*)&ATb[(size_t)w * 512 + kk * 32 + kg * 8]; \
            }                                                                      \
            _Pragma("unroll") for (int mt = 0; mt < 4; mt++)                       \
                _Pragma("unroll") for (int nt = 0; nt < 4; nt++)                   \
                    acc[mt][nt] = __builtin_amdgcn_mfma_f32_16x16x32_bf16(         \
                        afr[mt], bfr[nt], acc[mt][nt], 0, 0, 0);                   \
        }                                                                          \
        _Pragma("unroll") for (int mt = 0; mt < 4; mt++)                           \
            _Pragma("unroll") for (int nt = 0; nt < 4; nt++) {                     \
                const int w = wave * 64 + nt * 16 + colb;                          \
                _Pragma("unroll") for (int r = 0; r < 4; r++) {                    \
                    const int row = mt * 16 + kg * 4 + r;                          \
                    Y[WR][row * 512 + (((w >> 3) ^ (row & 15)) << 3) + (w & 7)] =  \
                        (u16)f2bf(acc[mt][nt][r]);                                 \
                }                                                                  \
            }                                                                      \
    }

    OUTACC(0, 0);
    GEMM(0, 1);
    __syncthreads();
    OUTACC(1, 1);
    GEMM(1, 0);
    __syncthreads();
    OUTACC(2, 0);
    GEMM(0, 1);
    __syncthreads();
    OUTACC(3, 1);
#undef OUTACC
#undef GEMM

    // store tmp[o][l][v] (+bias): 16 colb lanes = 64B runs, coalesced
#pragma unroll
    for (int mt = 0; mt < 2; mt++)
#pragma unroll
        for (int nt = 0; nt < 8; nt++) {
            const int w = wave * 64 + (nt & 3) * 16 + colb;
            const int l = lp * 2 + (nt >> 2);
#pragma unroll
            for (int r = 0; r < 4; r++) {
                const int o = mt * 16 + kg * 4 + r;
                tmp[bH + (size_t)o * PLANE + (size_t)l * 512 + w] =
                    bias[o] + aco[mt][nt][r];
            }
        }
}

// ---- transT: out[b][o][v][l] = tmp[b][o][l][v] — both sides coalesced --------
__global__ __launch_bounds__(256) void transT(const float* __restrict__ tmp,
                                              float* __restrict__ out) {
    const int o = blockIdx.y, b = blockIdx.z;
    const int vt = blockIdx.x / 3, lt = blockIdx.x % 3;
    const int v0 = vt * 64, l0 = lt * 64;
    const int tid = threadIdx.x;
    __shared__ float T[64][65];
    const float* tp = tmp + (size_t)b * CHSTRIDE + (size_t)o * PLANE;
    float* op = out + (size_t)b * CHSTRIDE + (size_t)o * PLANE;

#pragma unroll
    for (int rep = 0; rep < 16; rep++) {
        const int idx = rep * 256 + tid;
        const int ll = idx >> 6, vv = idx & 63;    // read: v-contiguous lanes
        if (l0 + ll < L) T[ll][vv] = tp[(size_t)(l0 + ll) * 512 + v0 + vv];
    }
    __syncthreads();
#pragma unroll
    for (int rep = 0; rep < 16; rep++) {
        const int idx = rep * 256 + tid;
        const int vv = idx >> 6, ll = idx & 63;    // write: l-contiguous lanes
        if (l0 + ll < L) op[(size_t)(v0 + vv) * L + l0 + ll] = T[ll][vv];
    }
}

extern "C" void kernel_launch(void* const* d_in, const int* in_sizes, int n_in,
                              void* d_out, int out_size, void* d_ws, size_t ws_size,
                              hipStream_t stream) {
    const float* x = (const float*)d_in[0];
    const float* adj = (const float*)d_in[1];
    const float* W = (const float*)d_in[2];
    const float* bias = (const float*)d_in[3];
    float* out = (float*)d_out;

    char* ws = (char*)d_ws;
    u16* ATb = (u16*)ws;
    u16* Wb = (u16*)(ws + 524288);
    u16* hbuf = (u16*)(ws + HDRB);

    prep_b<<<V + 1, 256, 0, stream>>>(adj, W, ATb, Wb);

    // per batch: xa (2B) + tmp (4B) per element = 6 * CHSTRIDE bytes
    const size_t avail = ws_size > HDRB ? ws_size - HDRB : 0;
    int nbc = (int)(avail / ((size_t)6 * CHSTRIDE));
    if (nbc < 1) nbc = 1;                          // requires ws >= ~17.6 MB
    if (nbc > B_) nbc = B_;

    for (int b0 = 0; b0 < B_; b0 += nbc) {
        const int nb = (B_ - b0 < nbc) ? (B_ - b0) : nbc;
        const float* xb = x + (size_t)b0 * CHSTRIDE;
        float* outb = out + (size_t)b0 * CHSTRIDE;
        u16* xa = hbuf;
        float* tmp = (float*)(hbuf + (size_t)nbc * CHSTRIDE);

        cvtT<<<dim3(3, 8, nb * 32), 256, 0, stream>>>(xb, xa);
        mega<<<dim3(84, nb), 512, 0, stream>>>(xa, ATb, Wb, bias, tmp);
        transT<<<dim3(24, 32, nb), 256, 0, stream>>>(tmp, outb);
    }
}

// Round 12
// 613.612 us; speedup vs baseline: 3.0067x; 1.0522x over previous
//
#include <hip/hip_runtime.h>

#define V 512
#define L 168
#define PLANE 86016          // 512*168
#define CHSTRIDE 2752512     // 32*512*168 elements per batch
#define B_ 16
#define HDR4 (1u << 22)      // 4 MiB header: ATb,M2,M3,ANb (512KB each) + Wb

typedef __attribute__((ext_vector_type(8))) short s16x8;
typedef __attribute__((ext_vector_type(4))) float f32x4;
typedef unsigned short u16;

__device__ inline short f2bf(float f) {
    unsigned u = __builtin_bit_cast(unsigned, f);
    u += 0x7FFF + ((u >> 16) & 1);
    return (short)(u >> 16);
}
__device__ inline float bf2f(u16 s) {
    return __builtin_bit_cast(float, ((unsigned)s) << 16);
}
__device__ inline void gll16(const u16* g, u16* lds) {
    __builtin_amdgcn_global_load_lds(
        (const __attribute__((address_space(1))) void*)g,
        (__attribute__((address_space(3))) void*)lds, 16, 0, 0);
}

// ---- prep2: ATb[w][v]=bf16(anorm[v][w]); ANb[v][w] row-major; Wb = folded W' --
__global__ __launch_bounds__(256) void prep2(const float* __restrict__ adj,
                                             const float* __restrict__ W,
                                             u16* __restrict__ ATb,
                                             u16* __restrict__ ANb,
                                             u16* __restrict__ Wb) {
    if (blockIdx.x == V) {
        const float al = 0.05f, be = 0.95f;
        for (int i = threadIdx.x; i < 1024; i += 256) {
            const int o = i >> 5, c = i & 31;
            const float w0 = W[o * 128 + c];
            const float w1 = W[o * 128 + 32 + c];
            const float w2 = W[o * 128 + 64 + c];
            const float w3 = W[o * 128 + 96 + c];
            Wb[o * 128 + c]      = f2bf(w0 + al * (w1 + w2 + w3));
            Wb[o * 128 + 32 + c] = f2bf(be * (w1 + al * (w2 + w3)));
            Wb[o * 128 + 64 + c] = f2bf(be * be * (w2 + al * w3));
            Wb[o * 128 + 96 + c] = f2bf(be * be * be * w3);
        }
        return;
    }
    const int v = blockIdx.x;
    float s = 0.f;
    for (int w = threadIdx.x; w < V; w += 256)
        s += adj[v * V + w] + (w == v ? 1.f : 0.f);
    __shared__ float red[256];
    red[threadIdx.x] = s;
    __syncthreads();
    for (int off = 128; off > 0; off >>= 1) {
        if ((int)threadIdx.x < off) red[threadIdx.x] += red[threadIdx.x + off];
        __syncthreads();
    }
    const float inv = 1.f / red[0];
    for (int w = threadIdx.x; w < V; w += 256) {
        const short q = f2bf((adj[v * V + w] + (w == v ? 1.f : 0.f)) * inv);
        ATb[w * V + v] = q;      // (anorm^T)[w][v]
        ANb[v * V + w] = q;      // anorm[v][w]
    }
}

// ---- powk: OUT[w][v] = bf16( sum_u X[w][u] * ANb[v][u] ) ----------------------
__global__ __launch_bounds__(256) void powk(const u16* __restrict__ X,
                                            const u16* __restrict__ ANb,
                                            u16* __restrict__ OUT) {
    const int w0 = (blockIdx.x >> 3) * 64, v0 = (blockIdx.x & 7) * 64;
    const int tid = threadIdx.x, lane = tid & 63, wave = tid >> 6;
    const int colb = lane & 15, kg = lane >> 4;
    f32x4 acc[4];
#pragma unroll
    for (int i = 0; i < 4; i++) acc[i] = (f32x4){0.f, 0.f, 0.f, 0.f};
#pragma unroll 4
    for (int kk = 0; kk < 16; kk++) {
        const int u = kk * 32 + kg * 8;
        const s16x8 bfr = *(const s16x8*)&ANb[(size_t)(v0 + wave * 16 + colb) * 512 + u];
#pragma unroll
        for (int mt = 0; mt < 4; mt++) {
            const s16x8 afr = *(const s16x8*)&X[(size_t)(w0 + mt * 16 + colb) * 512 + u];
            acc[mt] = __builtin_amdgcn_mfma_f32_16x16x32_bf16(afr, bfr, acc[mt], 0, 0, 0);
        }
    }
#pragma unroll
    for (int mt = 0; mt < 4; mt++)
#pragma unroll
        for (int r = 0; r < 4; r++)
            OUT[(size_t)(w0 + mt * 16 + kg * 4 + r) * 512 + v0 + wave * 16 + colb] =
                (u16)f2bf(acc[mt][r]);
}

// ---- cvtT: xa[b][(c,l)][v] = bf16(x[b][c][v][l]) — LDS-tiled (r7/r10-proven) -
__global__ __launch_bounds__(256) void cvtT(const float* __restrict__ x,
                                            u16* __restrict__ xa) {
    const int b = blockIdx.z >> 5, c = blockIdx.z & 31;
    const int v0 = blockIdx.y * 64, l0 = blockIdx.x * 64;
    const int tid = threadIdx.x;
    __shared__ float T[64][65];
    const float* xp = x + (size_t)b * CHSTRIDE + (size_t)c * PLANE;
    u16* xo = xa + (size_t)b * CHSTRIDE + (size_t)c * L * 512;
#pragma unroll
    for (int rep = 0; rep < 16; rep++) {
        const int idx = rep * 256 + tid;
        const int vv = idx >> 6, ll = idx & 63;
        if (l0 + ll < L) T[vv][ll] = xp[(size_t)(v0 + vv) * L + l0 + ll];
    }
    __syncthreads();
#pragma unroll
    for (int rep = 0; rep < 16; rep++) {
        const int idx = rep * 256 + tid;
        const int ll = idx >> 6, vv = idx & 63;
        if (l0 + ll < L)
            xo[(size_t)(l0 + ll) * 512 + v0 + vv] = f2bf(T[vv][ll]);
    }
}

// ---- propAll: p_k[n][w] = bf16( M_k @ xa ), k=1..3 in ONE dispatch ------------
__global__ __launch_bounds__(256, 2) void propAll(const u16* __restrict__ xa,
                                                  const u16* __restrict__ AS,
                                                  u16* __restrict__ pbuf,
                                                  long kstride) {
    const int b = blockIdx.z;
    const int n0 = (blockIdx.x / 12) * 128;
    const int wt = blockIdx.x % 12;
    const int k = wt >> 2, w0 = (wt & 3) * 128;
    const u16* Ak = AS + (size_t)k * 512 * 512;
    u16* dst = pbuf + (size_t)k * kstride;
    const int tid = threadIdx.x, lane = tid & 63, wave = tid >> 6;
    const int wm = wave >> 1, wn = wave & 1;
    const int colb = lane & 15, kg = lane >> 4;
    __shared__ __align__(16) u16 As[8 * 128 * 8];   // [oct][w][8]
    __shared__ __align__(16) u16 Bs[8 * 128 * 8];   // [oct][n][8]
    const size_t sB = (size_t)b * CHSTRIDE;
    const u16* srcb = xa + sB;

    f32x4 acc[4][4];
#pragma unroll
    for (int i = 0; i < 4; i++)
#pragma unroll
        for (int j = 0; j < 4; j++) acc[i][j] = (f32x4){0.f, 0.f, 0.f, 0.f};

    for (int v0 = 0; v0 < V; v0 += 64) {
        __syncthreads();
#pragma unroll
        for (int i = 0; i < 4; i++) {
            const int c = wave * 4 + i, oct = c >> 1, half = c & 1;
            const int row = half * 64 + lane;
            gll16(&Ak[(size_t)(w0 + row) * 512 + v0 + oct * 8],
                  &As[oct * 1024 + half * 512]);
            gll16(&srcb[(size_t)(n0 + row) * 512 + v0 + oct * 8],
                  &Bs[oct * 1024 + half * 512]);
        }
        __syncthreads();
#pragma unroll
        for (int kk = 0; kk < 2; kk++) {
            const int cq = kk * 4 + kg;
            s16x8 afr[4], bfr[4];
#pragma unroll
            for (int mt = 0; mt < 4; mt++)
                afr[mt] = *(const s16x8*)&As[cq * 1024 + (wm * 64 + mt * 16 + colb) * 8];
#pragma unroll
            for (int nt = 0; nt < 4; nt++)
                bfr[nt] = *(const s16x8*)&Bs[cq * 1024 + (wn * 64 + nt * 16 + colb) * 8];
#pragma unroll
            for (int mt = 0; mt < 4; mt++)
#pragma unroll
                for (int nt = 0; nt < 4; nt++)
                    acc[mt][nt] = __builtin_amdgcn_mfma_f32_16x16x32_bf16(afr[mt], bfr[nt],
                                                                          acc[mt][nt], 0, 0, 0);
        }
    }
#pragma unroll
    for (int mt = 0; mt < 4; mt++) {
        const int wrow = w0 + wm * 64 + mt * 16 + kg * 4;
#pragma unroll
        for (int nt = 0; nt < 4; nt++) {
            const int n = n0 + wn * 64 + nt * 16 + colb;
            ushort4 pk;
            pk.x = (u16)f2bf(acc[mt][nt][0]);
            pk.y = (u16)f2bf(acc[mt][nt][1]);
            pk.z = (u16)f2bf(acc[mt][nt][2]);
            pk.w = (u16)f2bf(acc[mt][nt][3]);
            *(ushort4*)&dst[sB + (size_t)n * 512 + wrow] = pk;
        }
    }
}

// ---- outconv_nv: tmpb[o][l][v] = bf16(bias + W' @ [xa,p1,p2,p3]) --------------
// grid.x = 8*168: vt = x/168 (v-tile of 64), l = x%168. (r11 bug: was &255 OOB)
__global__ __launch_bounds__(256) void outconv_nv(const u16* __restrict__ xa,
                                                  const u16* __restrict__ p1,
                                                  const u16* __restrict__ p2,
                                                  const u16* __restrict__ p3,
                                                  const u16* __restrict__ Wb,
                                                  const float* __restrict__ bias,
                                                  u16* __restrict__ tmpb) {
    const int b = blockIdx.y;
    const int vt = blockIdx.x / L, l = blockIdx.x % L;
    if (l >= L) return;
    const int v0 = vt * 64;
    const int tid = threadIdx.x, lane = tid & 63, wave = tid >> 6;
    const int colb = lane & 15, kg = lane >> 4;
    __shared__ __align__(16) u16 Hs[16 * 64 * 8];  // 16 KB
    const size_t bH = (size_t)b * CHSTRIDE;
    const u16* bufs[4] = {xa, p1, p2, p3};

    {
        const int vv = tid & 63;
#pragma unroll
        for (int p = 0; p < 4; p++) {
            const int m = wave + p * 4;                 // kc-octet m: buf m>>2, c-octet m&3
            const u16* srcp = bufs[m >> 2] + bH;
            s16x8 t;
#pragma unroll
            for (int j = 0; j < 8; j++)
                t[j] = (short)srcp[((size_t)((m & 3) * 8 + j) * L + l) * 512 + v0 + vv];
            *(s16x8*)&Hs[m * 512 + vv * 8] = t;
        }
    }
    __syncthreads();

    f32x4 acc[2];
    acc[0] = (f32x4){0.f, 0.f, 0.f, 0.f};
    acc[1] = acc[0];
#pragma unroll
    for (int kk = 0; kk < 4; kk++) {
        const s16x8 bfr = *(const s16x8*)&Hs[(kk * 4 + kg) * 512 + (wave * 16 + colb) * 8];
#pragma unroll
        for (int mt = 0; mt < 2; mt++) {
            const s16x8 afr = *(const s16x8*)&Wb[(mt * 16 + colb) * 128 + kk * 32 + kg * 8];
            acc[mt] = __builtin_amdgcn_mfma_f32_16x16x32_bf16(afr, bfr, acc[mt], 0, 0, 0);
        }
    }
#pragma unroll
    for (int mt = 0; mt < 2; mt++)
#pragma unroll
        for (int r = 0; r < 4; r++) {
            const int o = mt * 16 + kg * 4 + r;
            tmpb[bH + (size_t)o * PLANE + (size_t)l * 512 + v0 + wave * 16 + colb] =
                (u16)f2bf(bias[o] + acc[mt][r]);
        }
}

// ---- transT_b: out[b][o][v][l] = f32(tmpb[b][o][l][v]) ------------------------
__global__ __launch_bounds__(256) void transT_b(const u16* __restrict__ tmpb,
                                                float* __restrict__ out) {
    const int o = blockIdx.y, b = blockIdx.z;
    const int vt = blockIdx.x / 3, lt = blockIdx.x % 3;
    const int v0 = vt * 64, l0 = lt * 64;
    const int tid = threadIdx.x;
    __shared__ float T[64][65];
    const u16* tp = tmpb + (size_t)b * CHSTRIDE + (size_t)o * PLANE;
    float* op = out + (size_t)b * CHSTRIDE + (size_t)o * PLANE;
#pragma unroll
    for (int rep = 0; rep < 16; rep++) {
        const int idx = rep * 256 + tid;
        const int ll = idx >> 6, vv = idx & 63;    // read: v-contiguous lanes
        if (l0 + ll < L) T[ll][vv] = bf2f(tp[(size_t)(l0 + ll) * 512 + v0 + vv]);
    }
    __syncthreads();
#pragma unroll
    for (int rep = 0; rep < 16; rep++) {
        const int idx = rep * 256 + tid;
        const int vv = idx >> 6, ll = idx & 63;    // write: l-contiguous lanes
        if (l0 + ll < L) op[(size_t)(v0 + vv) * L + l0 + ll] = T[ll][vv];
    }
}

extern "C" void kernel_launch(void* const* d_in, const int* in_sizes, int n_in,
                              void* d_out, int out_size, void* d_ws, size_t ws_size,
                              hipStream_t stream) {
    const float* x = (const float*)d_in[0];
    const float* adj = (const float*)d_in[1];
    const float* W = (const float*)d_in[2];
    const float* bias = (const float*)d_in[3];
    float* out = (float*)d_out;

    u16* AS = (u16*)d_ws;                     // [M1;M2;M3], 3 x 262144 elems
    u16* ATb = AS;
    u16* M2 = AS + 262144;
    u16* M3 = AS + 2 * 262144;
    u16* ANb = AS + 3 * 262144;
    u16* Wb = AS + 4 * 262144;
    u16* hbuf = (u16*)((char*)d_ws + HDR4);

    prep2<<<V + 1, 256, 0, stream>>>(adj, W, ATb, ANb, Wb);
    powk<<<64, 256, 0, stream>>>(ATb, ANb, M2);
    powk<<<64, 256, 0, stream>>>(M2, ANb, M3);

    // per batch: xa + p1 + p2 + p3 + tmpb, all bf16 = 10 * CHSTRIDE bytes
    const size_t avail = ws_size > HDR4 ? ws_size - HDR4 : 0;
    int nbc = (int)(avail / ((size_t)10 * CHSTRIDE));
    if (nbc < 1) nbc = 1;                     // requires ws >= ~31.5 MB
    if (nbc > B_) nbc = B_;
    const long kstride = (long)nbc * CHSTRIDE;

    for (int b0 = 0; b0 < B_; b0 += nbc) {
        const int nb = (B_ - b0 < nbc) ? (B_ - b0) : nbc;
        const float* xb = x + (size_t)b0 * CHSTRIDE;
        float* outb = out + (size_t)b0 * CHSTRIDE;
        u16* xa = hbuf;
        u16* p1 = hbuf + kstride;
        u16* p2 = hbuf + 2 * kstride;
        u16* p3 = hbuf + 3 * kstride;
        u16* tmpb = hbuf + 4 * kstride;

        cvtT<<<dim3(3, 8, nb * 32), 256, 0, stream>>>(xb, xa);
        propAll<<<dim3(42 * 12, 1, nb), 256, 0, stream>>>(xa, AS, p1, kstride);
        outconv_nv<<<dim3(8 * L, nb), 256, 0, stream>>>(xa, p1, p2, p3, Wb, bias, tmpb);
        transT_b<<<dim3(24, 32, nb), 256, 0, stream>>>(tmpb, outb);
    }
}

// Round 13
// 606.045 us; speedup vs baseline: 3.0443x; 1.0125x over previous
//
#include <hip/hip_runtime.h>

#define V 512
#define L 168
#define PLANE 86016          // 512*168
#define CHSTRIDE 2752512     // 32*512*168 elements per batch
#define B_ 16
#define HDR4 (1u << 22)      // 4 MiB header: ATb,M2,M3,ANb (512KB each) + Wb

typedef __attribute__((ext_vector_type(8))) short s16x8;
typedef __attribute__((ext_vector_type(4))) float f32x4;
typedef unsigned short u16;

__device__ inline short f2bf(float f) {
    unsigned u = __builtin_bit_cast(unsigned, f);
    u += 0x7FFF + ((u >> 16) & 1);
    return (short)(u >> 16);
}
__device__ inline float bf2f(u16 s) {
    return __builtin_bit_cast(float, ((unsigned)s) << 16);
}
__device__ inline void gll16(const u16* g, u16* lds) {
    __builtin_amdgcn_global_load_lds(
        (const __attribute__((address_space(1))) void*)g,
        (__attribute__((address_space(3))) void*)lds, 16, 0, 0);
}

// ---- prep2: ATb[w][v]=bf16(anorm[v][w]); ANb[v][w] row-major; Wb = folded W' --
__global__ __launch_bounds__(256) void prep2(const float* __restrict__ adj,
                                             const float* __restrict__ W,
                                             u16* __restrict__ ATb,
                                             u16* __restrict__ ANb,
                                             u16* __restrict__ Wb) {
    if (blockIdx.x == V) {
        const float al = 0.05f, be = 0.95f;
        for (int i = threadIdx.x; i < 1024; i += 256) {
            const int o = i >> 5, c = i & 31;
            const float w0 = W[o * 128 + c];
            const float w1 = W[o * 128 + 32 + c];
            const float w2 = W[o * 128 + 64 + c];
            const float w3 = W[o * 128 + 96 + c];
            Wb[o * 128 + c]      = f2bf(w0 + al * (w1 + w2 + w3));
            Wb[o * 128 + 32 + c] = f2bf(be * (w1 + al * (w2 + w3)));
            Wb[o * 128 + 64 + c] = f2bf(be * be * (w2 + al * w3));
            Wb[o * 128 + 96 + c] = f2bf(be * be * be * w3);
        }
        return;
    }
    const int v = blockIdx.x;
    float s = 0.f;
    for (int w = threadIdx.x; w < V; w += 256)
        s += adj[v * V + w] + (w == v ? 1.f : 0.f);
    __shared__ float red[256];
    red[threadIdx.x] = s;
    __syncthreads();
    for (int off = 128; off > 0; off >>= 1) {
        if ((int)threadIdx.x < off) red[threadIdx.x] += red[threadIdx.x + off];
        __syncthreads();
    }
    const float inv = 1.f / red[0];
    for (int w = threadIdx.x; w < V; w += 256) {
        const short q = f2bf((adj[v * V + w] + (w == v ? 1.f : 0.f)) * inv);
        ATb[w * V + v] = q;      // (anorm^T)[w][v]
        ANb[v * V + w] = q;      // anorm[v][w]
    }
}

// ---- powk: OUT[w][v] = bf16( sum_u X[w][u] * ANb[v][u] ) ----------------------
__global__ __launch_bounds__(256) void powk(const u16* __restrict__ X,
                                            const u16* __restrict__ ANb,
                                            u16* __restrict__ OUT) {
    const int w0 = (blockIdx.x >> 3) * 64, v0 = (blockIdx.x & 7) * 64;
    const int tid = threadIdx.x, lane = tid & 63, wave = tid >> 6;
    const int colb = lane & 15, kg = lane >> 4;
    f32x4 acc[4];
#pragma unroll
    for (int i = 0; i < 4; i++) acc[i] = (f32x4){0.f, 0.f, 0.f, 0.f};
#pragma unroll 4
    for (int kk = 0; kk < 16; kk++) {
        const int u = kk * 32 + kg * 8;
        const s16x8 bfr = *(const s16x8*)&ANb[(size_t)(v0 + wave * 16 + colb) * 512 + u];
#pragma unroll
        for (int mt = 0; mt < 4; mt++) {
            const s16x8 afr = *(const s16x8*)&X[(size_t)(w0 + mt * 16 + colb) * 512 + u];
            acc[mt] = __builtin_amdgcn_mfma_f32_16x16x32_bf16(afr, bfr, acc[mt], 0, 0, 0);
        }
    }
#pragma unroll
    for (int mt = 0; mt < 4; mt++)
#pragma unroll
        for (int r = 0; r < 4; r++)
            OUT[(size_t)(w0 + mt * 16 + kg * 4 + r) * 512 + v0 + wave * 16 + colb] =
                (u16)f2bf(acc[mt][r]);
}

// ---- cvtT: xa[b][(c,l)][v] = bf16(x[b][c][v][l]) — LDS-tiled (r7/r10-proven) -
__global__ __launch_bounds__(256) void cvtT(const float* __restrict__ x,
                                            u16* __restrict__ xa) {
    const int b = blockIdx.z >> 5, c = blockIdx.z & 31;
    const int v0 = blockIdx.y * 64, l0 = blockIdx.x * 64;
    const int tid = threadIdx.x;
    __shared__ float T[64][65];
    const float* xp = x + (size_t)b * CHSTRIDE + (size_t)c * PLANE;
    u16* xo = xa + (size_t)b * CHSTRIDE + (size_t)c * L * 512;
#pragma unroll
    for (int rep = 0; rep < 16; rep++) {
        const int idx = rep * 256 + tid;
        const int vv = idx >> 6, ll = idx & 63;
        if (l0 + ll < L) T[vv][ll] = xp[(size_t)(v0 + vv) * L + l0 + ll];
    }
    __syncthreads();
#pragma unroll
    for (int rep = 0; rep < 16; rep++) {
        const int idx = rep * 256 + tid;
        const int ll = idx >> 6, vv = idx & 63;
        if (l0 + ll < L)
            xo[(size_t)(l0 + ll) * 512 + v0 + vv] = f2bf(T[vv][ll]);
    }
}

// ---- propAll: p_k[n][w] = bf16( M_k @ xa ), k=1..3 in ONE dispatch ------------
// XCD-chunked swizzle (T1): hw bid -> logical so each XCD owns ~5.25 contiguous
// n-panels; the 12 blocks sharing a panel all land on ONE XCD's L2.
// 504 blocks/batch-slice = 8 * 63 (bijective; slice-aligned since 504 % 8 == 0).
__global__ __launch_bounds__(256, 4) void propAll(const u16* __restrict__ xa,
                                                  const u16* __restrict__ AS,
                                                  u16* __restrict__ pbuf,
                                                  long kstride) {
    const int b = blockIdx.z;
    const int logical = (blockIdx.x & 7) * 63 + (blockIdx.x >> 3);
    const int n0 = (logical / 12) * 128;
    const int wt = logical % 12;
    const int k = wt >> 2, w0 = (wt & 3) * 128;
    const u16* Ak = AS + (size_t)k * 512 * 512;
    u16* dst = pbuf + (size_t)k * kstride;
    const int tid = threadIdx.x, lane = tid & 63, wave = tid >> 6;
    const int wm = wave >> 1, wn = wave & 1;
    const int colb = lane & 15, kg = lane >> 4;
    __shared__ __align__(16) u16 As[8 * 128 * 8];   // [oct][w][8]
    __shared__ __align__(16) u16 Bs[8 * 128 * 8];   // [oct][n][8]
    const size_t sB = (size_t)b * CHSTRIDE;
    const u16* srcb = xa + sB;

    f32x4 acc[4][4];
#pragma unroll
    for (int i = 0; i < 4; i++)
#pragma unroll
        for (int j = 0; j < 4; j++) acc[i][j] = (f32x4){0.f, 0.f, 0.f, 0.f};

    for (int v0 = 0; v0 < V; v0 += 64) {
        __syncthreads();
#pragma unroll
        for (int i = 0; i < 4; i++) {
            const int c = wave * 4 + i, oct = c >> 1, half = c & 1;
            const int row = half * 64 + lane;
            gll16(&Ak[(size_t)(w0 + row) * 512 + v0 + oct * 8],
                  &As[oct * 1024 + half * 512]);
            gll16(&srcb[(size_t)(n0 + row) * 512 + v0 + oct * 8],
                  &Bs[oct * 1024 + half * 512]);
        }
        __syncthreads();
#pragma unroll
        for (int kk = 0; kk < 2; kk++) {
            const int cq = kk * 4 + kg;
            s16x8 afr[4], bfr[4];
#pragma unroll
            for (int mt = 0; mt < 4; mt++)
                afr[mt] = *(const s16x8*)&As[cq * 1024 + (wm * 64 + mt * 16 + colb) * 8];
#pragma unroll
            for (int nt = 0; nt < 4; nt++)
                bfr[nt] = *(const s16x8*)&Bs[cq * 1024 + (wn * 64 + nt * 16 + colb) * 8];
#pragma unroll
            for (int mt = 0; mt < 4; mt++)
#pragma unroll
                for (int nt = 0; nt < 4; nt++)
                    acc[mt][nt] = __builtin_amdgcn_mfma_f32_16x16x32_bf16(afr[mt], bfr[nt],
                                                                          acc[mt][nt], 0, 0, 0);
        }
    }
#pragma unroll
    for (int mt = 0; mt < 4; mt++) {
        const int wrow = w0 + wm * 64 + mt * 16 + kg * 4;
#pragma unroll
        for (int nt = 0; nt < 4; nt++) {
            const int n = n0 + wn * 64 + nt * 16 + colb;
            ushort4 pk;
            pk.x = (u16)f2bf(acc[mt][nt][0]);
            pk.y = (u16)f2bf(acc[mt][nt][1]);
            pk.z = (u16)f2bf(acc[mt][nt][2]);
            pk.w = (u16)f2bf(acc[mt][nt][3]);
            *(ushort4*)&dst[sB + (size_t)n * 512 + wrow] = pk;
        }
    }
}

// ---- outconv_nv: tmpb[o][l][v] = bf16(bias + W' @ [xa,p1,p2,p3]) --------------
__global__ __launch_bounds__(256) void outconv_nv(const u16* __restrict__ xa,
                                                  const u16* __restrict__ p1,
                                                  const u16* __restrict__ p2,
                                                  const u16* __restrict__ p3,
                                                  const u16* __restrict__ Wb,
                                                  const float* __restrict__ bias,
                                                  u16* __restrict__ tmpb) {
    const int b = blockIdx.y;
    const int vt = blockIdx.x / L, l = blockIdx.x % L;
    const int v0 = vt * 64;
    const int tid = threadIdx.x, lane = tid & 63, wave = tid >> 6;
    const int colb = lane & 15, kg = lane >> 4;
    __shared__ __align__(16) u16 Hs[16 * 64 * 8];  // 16 KB
    const size_t bH = (size_t)b * CHSTRIDE;
    const u16* bufs[4] = {xa, p1, p2, p3};

    {
        const int vv = tid & 63;
#pragma unroll
        for (int p = 0; p < 4; p++) {
            const int m = wave + p * 4;                 // kc-octet m: buf m>>2, c-octet m&3
            const u16* srcp = bufs[m >> 2] + bH;
            s16x8 t;
#pragma unroll
            for (int j = 0; j < 8; j++)
                t[j] = (short)srcp[((size_t)((m & 3) * 8 + j) * L + l) * 512 + v0 + vv];
            *(s16x8*)&Hs[m * 512 + vv * 8] = t;
        }
    }
    __syncthreads();

    f32x4 acc[2];
    acc[0] = (f32x4){0.f, 0.f, 0.f, 0.f};
    acc[1] = acc[0];
#pragma unroll
    for (int kk = 0; kk < 4; kk++) {
        const s16x8 bfr = *(const s16x8*)&Hs[(kk * 4 + kg) * 512 + (wave * 16 + colb) * 8];
#pragma unroll
        for (int mt = 0; mt < 2; mt++) {
            const s16x8 afr = *(const s16x8*)&Wb[(mt * 16 + colb) * 128 + kk * 32 + kg * 8];
            acc[mt] = __builtin_amdgcn_mfma_f32_16x16x32_bf16(afr, bfr, acc[mt], 0, 0, 0);
        }
    }
#pragma unroll
    for (int mt = 0; mt < 2; mt++)
#pragma unroll
        for (int r = 0; r < 4; r++) {
            const int o = mt * 16 + kg * 4 + r;
            tmpb[bH + (size_t)o * PLANE + (size_t)l * 512 + v0 + wave * 16 + colb] =
                (u16)f2bf(bias[o] + acc[mt][r]);
        }
}

// ---- transT_b: out[b][o][v][l] = f32(tmpb[b][o][l][v]) ------------------------
__global__ __launch_bounds__(256) void transT_b(const u16* __restrict__ tmpb,
                                                float* __restrict__ out) {
    const int o = blockIdx.y, b = blockIdx.z;
    const int vt = blockIdx.x / 3, lt = blockIdx.x % 3;
    const int v0 = vt * 64, l0 = lt * 64;
    const int tid = threadIdx.x;
    __shared__ float T[64][65];
    const u16* tp = tmpb + (size_t)b * CHSTRIDE + (size_t)o * PLANE;
    float* op = out + (size_t)b * CHSTRIDE + (size_t)o * PLANE;
#pragma unroll
    for (int rep = 0; rep < 16; rep++) {
        const int idx = rep * 256 + tid;
        const int ll = idx >> 6, vv = idx & 63;    // read: v-contiguous lanes
        if (l0 + ll < L) T[ll][vv] = bf2f(tp[(size_t)(l0 + ll) * 512 + v0 + vv]);
    }
    __syncthreads();
#pragma unroll
    for (int rep = 0; rep < 16; rep++) {
        const int idx = rep * 256 + tid;
        const int vv = idx >> 6, ll = idx & 63;    // write: l-contiguous lanes
        if (l0 + ll < L) op[(size_t)(v0 + vv) * L + l0 + ll] = T[ll][vv];
    }
}

extern "C" void kernel_launch(void* const* d_in, const int* in_sizes, int n_in,
                              void* d_out, int out_size, void* d_ws, size_t ws_size,
                              hipStream_t stream) {
    const float* x = (const float*)d_in[0];
    const float* adj = (const float*)d_in[1];
    const float* W = (const float*)d_in[2];
    const float* bias = (const float*)d_in[3];
    float* out = (float*)d_out;

    u16* AS = (u16*)d_ws;                     // [M1;M2;M3], 3 x 262144 elems
    u16* ATb = AS;
    u16* M2 = AS + 262144;
    u16* M3 = AS + 2 * 262144;
    u16* ANb = AS + 3 * 262144;
    u16* Wb = AS + 4 * 262144;
    u16* hbuf = (u16*)((char*)d_ws + HDR4);

    prep2<<<V + 1, 256, 0, stream>>>(adj, W, ATb, ANb, Wb);
    powk<<<64, 256, 0, stream>>>(ATb, ANb, M2);
    powk<<<64, 256, 0, stream>>>(M2, ANb, M3);

    // per batch: xa + p1 + p2 + p3 + tmpb, all bf16 = 10 * CHSTRIDE bytes
    const size_t avail = ws_size > HDR4 ? ws_size - HDR4 : 0;
    int nbc = (int)(avail / ((size_t)10 * CHSTRIDE));
    if (nbc < 1) nbc = 1;                     // requires ws >= ~31.5 MB
    if (nbc > B_) nbc = B_;
    const long kstride = (long)nbc * CHSTRIDE;

    for (int b0 = 0; b0 < B_; b0 += nbc) {
        const int nb = (B_ - b0 < nbc) ? (B_ - b0) : nbc;
        const float* xb = x + (size_t)b0 * CHSTRIDE;
        float* outb = out + (size_t)b0 * CHSTRIDE;
        u16* xa = hbuf;
        u16* p1 = hbuf + kstride;
        u16* p2 = hbuf + 2 * kstride;
        u16* p3 = hbuf + 3 * kstride;
        u16* tmpb = hbuf + 4 * kstride;

        cvtT<<<dim3(3, 8, nb * 32), 256, 0, stream>>>(xb, xa);
        propAll<<<dim3(42 * 12, 1, nb), 256, 0, stream>>>(xa, AS, p1, kstride);
        outconv_nv<<<dim3(8 * L, nb), 256, 0, stream>>>(xa, p1, p2, p3, Wb, bias, tmpb);
        transT_b<<<dim3(24, 32, nb), 256, 0, stream>>>(tmpb, outb);
    }
}

// Round 14
// 587.521 us; speedup vs baseline: 3.1403x; 1.0315x over previous
//
#include <hip/hip_runtime.h>

#define V 512
#define L 168
#define PLANE 86016          // 512*168
#define CHSTRIDE 2752512     // 32*512*168 elements per batch
#define B_ 16
#define HDR4 (1u << 22)      // 4 MiB header: ATb,M2,M3,ANb (512KB each) + Wb

typedef __attribute__((ext_vector_type(8))) short s16x8;
typedef __attribute__((ext_vector_type(4))) float f32x4;
typedef unsigned short u16;

__device__ inline short f2bf(float f) {
    unsigned u = __builtin_bit_cast(unsigned, f);
    u += 0x7FFF + ((u >> 16) & 1);
    return (short)(u >> 16);
}
__device__ inline float bf2f(u16 s) {
    return __builtin_bit_cast(float, ((unsigned)s) << 16);
}
__device__ inline void gll16(const u16* g, u16* lds) {
    __builtin_amdgcn_global_load_lds(
        (const __attribute__((address_space(1))) void*)g,
        (__attribute__((address_space(3))) void*)lds, 16, 0, 0);
}

// ---- prep2: ATb[w][v]=bf16(anorm[v][w]); ANb[v][w] row-major; Wb = folded W' --
__global__ __launch_bounds__(256) void prep2(const float* __restrict__ adj,
                                             const float* __restrict__ W,
                                             u16* __restrict__ ATb,
                                             u16* __restrict__ ANb,
                                             u16* __restrict__ Wb) {
    if (blockIdx.x == V) {
        const float al = 0.05f, be = 0.95f;
        for (int i = threadIdx.x; i < 1024; i += 256) {
            const int o = i >> 5, c = i & 31;
            const float w0 = W[o * 128 + c];
            const float w1 = W[o * 128 + 32 + c];
            const float w2 = W[o * 128 + 64 + c];
            const float w3 = W[o * 128 + 96 + c];
            Wb[o * 128 + c]      = f2bf(w0 + al * (w1 + w2 + w3));
            Wb[o * 128 + 32 + c] = f2bf(be * (w1 + al * (w2 + w3)));
            Wb[o * 128 + 64 + c] = f2bf(be * be * (w2 + al * w3));
            Wb[o * 128 + 96 + c] = f2bf(be * be * be * w3);
        }
        return;
    }
    const int v = blockIdx.x;
    float s = 0.f;
    for (int w = threadIdx.x; w < V; w += 256)
        s += adj[v * V + w] + (w == v ? 1.f : 0.f);
    __shared__ float red[256];
    red[threadIdx.x] = s;
    __syncthreads();
    for (int off = 128; off > 0; off >>= 1) {
        if ((int)threadIdx.x < off) red[threadIdx.x] += red[threadIdx.x + off];
        __syncthreads();
    }
    const float inv = 1.f / red[0];
    for (int w = threadIdx.x; w < V; w += 256) {
        const short q = f2bf((adj[v * V + w] + (w == v ? 1.f : 0.f)) * inv);
        ATb[w * V + v] = q;      // (anorm^T)[w][v]
        ANb[v * V + w] = q;      // anorm[v][w]
    }
}

// ---- powk: OUT[w][v] = bf16( sum_u X[w][u] * ANb[v][u] ) ----------------------
__global__ __launch_bounds__(256) void powk(const u16* __restrict__ X,
                                            const u16* __restrict__ ANb,
                                            u16* __restrict__ OUT) {
    const int w0 = (blockIdx.x >> 3) * 64, v0 = (blockIdx.x & 7) * 64;
    const int tid = threadIdx.x, lane = tid & 63, wave = tid >> 6;
    const int colb = lane & 15, kg = lane >> 4;
    f32x4 acc[4];
#pragma unroll
    for (int i = 0; i < 4; i++) acc[i] = (f32x4){0.f, 0.f, 0.f, 0.f};
#pragma unroll 4
    for (int kk = 0; kk < 16; kk++) {
        const int u = kk * 32 + kg * 8;
        const s16x8 bfr = *(const s16x8*)&ANb[(size_t)(v0 + wave * 16 + colb) * 512 + u];
#pragma unroll
        for (int mt = 0; mt < 4; mt++) {
            const s16x8 afr = *(const s16x8*)&X[(size_t)(w0 + mt * 16 + colb) * 512 + u];
            acc[mt] = __builtin_amdgcn_mfma_f32_16x16x32_bf16(afr, bfr, acc[mt], 0, 0, 0);
        }
    }
#pragma unroll
    for (int mt = 0; mt < 4; mt++)
#pragma unroll
        for (int r = 0; r < 4; r++)
            OUT[(size_t)(w0 + mt * 16 + kg * 4 + r) * 512 + v0 + wave * 16 + colb] =
                (u16)f2bf(acc[mt][r]);
}

// ---- cvtT: xa[b][(c,l)][v] = bf16(x[b][c][v][l]) — LDS-tiled (r7/r10-proven) -
__global__ __launch_bounds__(256) void cvtT(const float* __restrict__ x,
                                            u16* __restrict__ xa) {
    const int b = blockIdx.z >> 5, c = blockIdx.z & 31;
    const int v0 = blockIdx.y * 64, l0 = blockIdx.x * 64;
    const int tid = threadIdx.x;
    __shared__ float T[64][65];
    const float* xp = x + (size_t)b * CHSTRIDE + (size_t)c * PLANE;
    u16* xo = xa + (size_t)b * CHSTRIDE + (size_t)c * L * 512;
#pragma unroll
    for (int rep = 0; rep < 16; rep++) {
        const int idx = rep * 256 + tid;
        const int vv = idx >> 6, ll = idx & 63;
        if (l0 + ll < L) T[vv][ll] = xp[(size_t)(v0 + vv) * L + l0 + ll];
    }
    __syncthreads();
#pragma unroll
    for (int rep = 0; rep < 16; rep++) {
        const int idx = rep * 256 + tid;
        const int ll = idx >> 6, vv = idx & 63;
        if (l0 + ll < L)
            xo[(size_t)(l0 + ll) * 512 + v0 + vv] = f2bf(T[vv][ll]);
    }
}

// ---- propAll: p_k[n][w] = bf16( M_k @ xa ), k=1..3, ONE dispatch --------------
// T1 XCD swizzle (r13-proven, FETCH 6x) + T3-minimum 2-phase dbuf: stage(t+1)
// issued BEFORE MFMA(t), one __syncthreads per iter (vmcnt(0) lands post-MFMA).
// Epilogue: C bounced through LDS -> 4x256B-coalesced 16B stores.
__global__ __launch_bounds__(256, 2) void propAll(const u16* __restrict__ xa,
                                                  const u16* __restrict__ AS,
                                                  u16* __restrict__ pbuf,
                                                  long kstride) {
    const int b = blockIdx.z;
    const int logical = (blockIdx.x & 7) * 63 + (blockIdx.x >> 3);
    const int n0 = (logical / 12) * 128;
    const int wt = logical % 12;
    const int k = wt >> 2, w0 = (wt & 3) * 128;
    const u16* Ak = AS + (size_t)k * 512 * 512;
    u16* dst = pbuf + (size_t)k * kstride;
    const int tid = threadIdx.x, lane = tid & 63, wave = tid >> 6;
    const int wm = wave >> 1, wn = wave & 1;
    const int colb = lane & 15, kg = lane >> 4;
    __shared__ __align__(16) u16 SH[2][16384];   // [buf][ As 8192 | Bs 8192 ], 64 KB
    const size_t sB = (size_t)b * CHSTRIDE;
    const u16* srcb = xa + sB;

    f32x4 acc[4][4];
#pragma unroll
    for (int i = 0; i < 4; i++)
#pragma unroll
        for (int j = 0; j < 4; j++) acc[i][j] = (f32x4){0.f, 0.f, 0.f, 0.f};

#define STAGE(T, BUF)                                                             \
    {                                                                             \
        const int v0s = (T) * 64;                                                 \
        _Pragma("unroll") for (int i = 0; i < 4; i++) {                           \
            const int c = wave * 4 + i, oct = c >> 1, half = c & 1;               \
            const int row = half * 64 + lane;                                     \
            gll16(&Ak[(size_t)(w0 + row) * 512 + v0s + oct * 8],                  \
                  &SH[BUF][oct * 1024 + half * 512]);                             \
            gll16(&srcb[(size_t)(n0 + row) * 512 + v0s + oct * 8],                \
                  &SH[BUF][8192 + oct * 1024 + half * 512]);                      \
        }                                                                         \
    }

    STAGE(0, 0);
    __syncthreads();
#pragma unroll
    for (int t = 0; t < 8; t++) {
        const int buf = t & 1;
        if (t < 7) STAGE(t + 1, buf ^ 1);          // issue next tile's loads NOW
        __builtin_amdgcn_s_setprio(1);
#pragma unroll
        for (int kk = 0; kk < 2; kk++) {
            const int cq = kk * 4 + kg;
            s16x8 afr[4], bfr[4];
#pragma unroll
            for (int mt = 0; mt < 4; mt++)
                afr[mt] = *(const s16x8*)&SH[buf][cq * 1024 + (wm * 64 + mt * 16 + colb) * 8];
#pragma unroll
            for (int nt = 0; nt < 4; nt++)
                bfr[nt] = *(const s16x8*)&SH[buf][8192 + cq * 1024 + (wn * 64 + nt * 16 + colb) * 8];
#pragma unroll
            for (int mt = 0; mt < 4; mt++)
#pragma unroll
                for (int nt = 0; nt < 4; nt++)
                    acc[mt][nt] = __builtin_amdgcn_mfma_f32_16x16x32_bf16(afr[mt], bfr[nt],
                                                                          acc[mt][nt], 0, 0, 0);
        }
        __builtin_amdgcn_s_setprio(0);
        __syncthreads();   // drains the stage(t+1) loads (latency hidden by MFMA)
    }
#undef STAGE

    // epilogue: C -> LDS (pitch 136) -> coalesced stores (4 x 256B runs / instr)
    u16* Cs = &SH[0][0];                          // loop done; reuse both buffers
#pragma unroll
    for (int mt = 0; mt < 4; mt++) {
        const int wr = wm * 64 + mt * 16 + kg * 4;
#pragma unroll
        for (int nt = 0; nt < 4; nt++) {
            const int n = wn * 64 + nt * 16 + colb;
            ushort4 pk;
            pk.x = (u16)f2bf(acc[mt][nt][0]);
            pk.y = (u16)f2bf(acc[mt][nt][1]);
            pk.z = (u16)f2bf(acc[mt][nt][2]);
            pk.w = (u16)f2bf(acc[mt][nt][3]);
            *(ushort4*)&Cs[n * 136 + wr] = pk;
        }
    }
    __syncthreads();
    {
        const int wch = tid & 15, nr = tid >> 4;  // nr 0..15
#pragma unroll
        for (int j = 0; j < 8; j++) {
            const int n = j * 16 + nr;
            const s16x8 val = *(const s16x8*)&Cs[n * 136 + wch * 8];
            *(s16x8*)&dst[sB + (size_t)(n0 + n) * 512 + w0 + wch * 8] = val;
        }
    }
}

// ---- outconv_nv: tmpb[o][l][v] = bf16(bias + W' @ [xa,p1,p2,p3]) --------------
__global__ __launch_bounds__(256) void outconv_nv(const u16* __restrict__ xa,
                                                  const u16* __restrict__ p1,
                                                  const u16* __restrict__ p2,
                                                  const u16* __restrict__ p3,
                                                  const u16* __restrict__ Wb,
                                                  const float* __restrict__ bias,
                                                  u16* __restrict__ tmpb) {
    const int b = blockIdx.y;
    const int vt = blockIdx.x / L, l = blockIdx.x % L;
    const int v0 = vt * 64;
    const int tid = threadIdx.x, lane = tid & 63, wave = tid >> 6;
    const int colb = lane & 15, kg = lane >> 4;
    __shared__ __align__(16) u16 Hs[16 * 64 * 8];  // 16 KB
    const size_t bH = (size_t)b * CHSTRIDE;
    const u16* bufs[4] = {xa, p1, p2, p3};

    {
        const int vv = tid & 63;
#pragma unroll
        for (int p = 0; p < 4; p++) {
            const int m = wave + p * 4;                 // kc-octet m: buf m>>2, c-octet m&3
            const u16* srcp = bufs[m >> 2] + bH;
            s16x8 t;
#pragma unroll
            for (int j = 0; j < 8; j++)
                t[j] = (short)srcp[((size_t)((m & 3) * 8 + j) * L + l) * 512 + v0 + vv];
            *(s16x8*)&Hs[m * 512 + vv * 8] = t;
        }
    }
    __syncthreads();

    f32x4 acc[2];
    acc[0] = (f32x4){0.f, 0.f, 0.f, 0.f};
    acc[1] = acc[0];
#pragma unroll
    for (int kk = 0; kk < 4; kk++) {
        const s16x8 bfr = *(const s16x8*)&Hs[(kk * 4 + kg) * 512 + (wave * 16 + colb) * 8];
#pragma unroll
        for (int mt = 0; mt < 2; mt++) {
            const s16x8 afr = *(const s16x8*)&Wb[(mt * 16 + colb) * 128 + kk * 32 + kg * 8];
            acc[mt] = __builtin_amdgcn_mfma_f32_16x16x32_bf16(afr, bfr, acc[mt], 0, 0, 0);
        }
    }
#pragma unroll
    for (int mt = 0; mt < 2; mt++)
#pragma unroll
        for (int r = 0; r < 4; r++) {
            const int o = mt * 16 + kg * 4 + r;
            tmpb[bH + (size_t)o * PLANE + (size_t)l * 512 + v0 + wave * 16 + colb] =
                (u16)f2bf(bias[o] + acc[mt][r]);
        }
}

// ---- transT_b: out[b][o][v][l] = f32(tmpb[b][o][l][v]) ------------------------
__global__ __launch_bounds__(256) void transT_b(const u16* __restrict__ tmpb,
                                                float* __restrict__ out) {
    const int o = blockIdx.y, b = blockIdx.z;
    const int vt = blockIdx.x / 3, lt = blockIdx.x % 3;
    const int v0 = vt * 64, l0 = lt * 64;
    const int tid = threadIdx.x;
    __shared__ float T[64][65];
    const u16* tp = tmpb + (size_t)b * CHSTRIDE + (size_t)o * PLANE;
    float* op = out + (size_t)b * CHSTRIDE + (size_t)o * PLANE;
#pragma unroll
    for (int rep = 0; rep < 16; rep++) {
        const int idx = rep * 256 + tid;
        const int ll = idx >> 6, vv = idx & 63;    // read: v-contiguous lanes
        if (l0 + ll < L) T[ll][vv] = bf2f(tp[(size_t)(l0 + ll) * 512 + v0 + vv]);
    }
    __syncthreads();
#pragma unroll
    for (int rep = 0; rep < 16; rep++) {
        const int idx = rep * 256 + tid;
        const int vv = idx >> 6, ll = idx & 63;    // write: l-contiguous lanes
        if (l0 + ll < L) op[(size_t)(v0 + vv) * L + l0 + ll] = T[ll][vv];
    }
}

extern "C" void kernel_launch(void* const* d_in, const int* in_sizes, int n_in,
                              void* d_out, int out_size, void* d_ws, size_t ws_size,
                              hipStream_t stream) {
    const float* x = (const float*)d_in[0];
    const float* adj = (const float*)d_in[1];
    const float* W = (const float*)d_in[2];
    const float* bias = (const float*)d_in[3];
    float* out = (float*)d_out;

    u16* AS = (u16*)d_ws;                     // [M1;M2;M3], 3 x 262144 elems
    u16* ATb = AS;
    u16* M2 = AS + 262144;
    u16* M3 = AS + 2 * 262144;
    u16* ANb = AS + 3 * 262144;
    u16* Wb = AS + 4 * 262144;
    u16* hbuf = (u16*)((char*)d_ws + HDR4);

    prep2<<<V + 1, 256, 0, stream>>>(adj, W, ATb, ANb, Wb);
    powk<<<64, 256, 0, stream>>>(ATb, ANb, M2);
    powk<<<64, 256, 0, stream>>>(M2, ANb, M3);

    // per batch: xa + p1 + p2 + p3 + tmpb, all bf16 = 10 * CHSTRIDE bytes
    const size_t avail = ws_size > HDR4 ? ws_size - HDR4 : 0;
    int nbc = (int)(avail / ((size_t)10 * CHSTRIDE));
    if (nbc < 1) nbc = 1;                     // requires ws >= ~31.5 MB
    if (nbc > B_) nbc = B_;
    const long kstride = (long)nbc * CHSTRIDE;

    for (int b0 = 0; b0 < B_; b0 += nbc) {
        const int nb = (B_ - b0 < nbc) ? (B_ - b0) : nbc;
        const float* xb = x + (size_t)b0 * CHSTRIDE;
        float* outb = out + (size_t)b0 * CHSTRIDE;
        u16* xa = hbuf;
        u16* p1 = hbuf + kstride;
        u16* p2 = hbuf + 2 * kstride;
        u16* p3 = hbuf + 3 * kstride;
        u16* tmpb = hbuf + 4 * kstride;

        cvtT<<<dim3(3, 8, nb * 32), 256, 0, stream>>>(xb, xa);
        propAll<<<dim3(42 * 12, 1, nb), 256, 0, stream>>>(xa, AS, p1, kstride);
        outconv_nv<<<dim3(8 * L, nb), 256, 0, stream>>>(xa, p1, p2, p3, Wb, bias, tmpb);
        transT_b<<<dim3(24, 32, nb), 256, 0, stream>>>(tmpb, outb);
    }
}